// Round 1
// baseline (646.056 us; speedup 1.0000x reference)
//
#include <hip/hip_runtime.h>
#include <hip/hip_bf16.h>

// Edge-MLP: out = relu(cat(v_i,v_j,e_ij) @ W1 + b1) @ W2 + b2
// E=1e6, d_in=160, HID=64, OUT=64. fp32 in/out, bf16 MFMA compute.
//
// Strategy: memory-bound (896 MB min traffic -> ~142us floor @6.3TB/s).
// mfma_f32_16x16x32_bf16, per-wave M-tile = 16 edges x N=64.
// K1=160 = 5 k-steps of 32, each entirely within one input array.
// Weights packed once/block into LDS in B-fragment order (lane-contiguous
// 16B -> conflict-free ds_read_b128). H round-trips LDS (stride 72 pad,
// 2-way bank alias = free) to convert C/D layout -> A layout.

typedef __bf16 bf16x8 __attribute__((ext_vector_type(8)));
typedef float  f32x4  __attribute__((ext_vector_type(4)));

__device__ inline bf16x8 cvt8(float4 a, float4 b) {
    bf16x8 o;
    o[0] = (__bf16)a.x; o[1] = (__bf16)a.y; o[2] = (__bf16)a.z; o[3] = (__bf16)a.w;
    o[4] = (__bf16)b.x; o[5] = (__bf16)b.y; o[6] = (__bf16)b.z; o[7] = (__bf16)b.w;
    return o;
}

__global__ __launch_bounds__(256, 3)
void edge_mlp_kernel(const float* __restrict__ v_i,
                     const float* __restrict__ v_j,
                     const float* __restrict__ e_ij,
                     const float* __restrict__ W1,
                     const float* __restrict__ b1,
                     const float* __restrict__ W2,
                     const float* __restrict__ b2,
                     float* __restrict__ out,
                     int E)
{
    // B-fragments: frag (s,n): lane l holds W[s*32 + (l>>4)*8 + j][n*16 + (l&15)], j=0..7
    __shared__ __align__(16) __bf16 w1f[20 * 64 * 8];   // 20 KB: 5 k-steps x 4 n-tiles
    __shared__ __align__(16) __bf16 w2f[8 * 64 * 8];    //  8 KB: 2 k-steps x 4 n-tiles
    __shared__ __align__(16) __bf16 hbuf[4][16 * 72];   //  9 KB: per-wave H, stride 72

    const int tid = threadIdx.x;

    // ---- pack W1 into fragment order (once per block; tiny, L2-cached) ----
    for (int idx = tid; idx < 20 * 64; idx += 256) {
        int f = idx >> 6, l = idx & 63;
        int s = f >> 2, n = f & 3;
        int kb = s * 32 + ((l >> 4) << 3);
        int c  = n * 16 + (l & 15);
        #pragma unroll
        for (int j = 0; j < 8; ++j)
            w1f[idx * 8 + j] = (__bf16)W1[(kb + j) * 64 + c];
    }
    // ---- pack W2 ----
    for (int idx = tid; idx < 8 * 64; idx += 256) {
        int f = idx >> 6, l = idx & 63;
        int s = f >> 2, n = f & 3;
        int kb = s * 32 + ((l >> 4) << 3);
        int c  = n * 16 + (l & 15);
        #pragma unroll
        for (int j = 0; j < 8; ++j)
            w2f[idx * 8 + j] = (__bf16)W2[(kb + j) * 64 + c];
    }
    __syncthreads();

    const int wave = tid >> 6;
    const int lane = tid & 63;
    const int q = lane >> 4;   // quad id (0..3)
    const int r = lane & 15;   // intra-quad lane (0..15)

    float b1v[4], b2v[4];
    #pragma unroll
    for (int n = 0; n < 4; ++n) {
        b1v[n] = b1[n * 16 + r];
        b2v[n] = b2[n * 16 + r];
    }

    __bf16* hb = hbuf[wave];

    const long long ntiles = ((long long)E + 15) >> 4;
    const long long stride = (long long)gridDim.x * 4;

    for (long long t = (long long)blockIdx.x * 4 + wave; t < ntiles; t += stride) {
        const long long e0 = t << 4;
        long long row = e0 + r;
        if (row > (long long)E - 1) row = (long long)E - 1;  // tail clamp

        // A-fragment loads: lane holds row (e0+r), k = q*8 + j within each k-step.
        // Wave-level: 16 rows x contiguous 128B -> full cache-line utilization.
        const float* pvi = v_i + row * 64 + q * 8;
        const float* pvj = v_j + row * 64 + q * 8;
        const float* pe  = e_ij + row * 32 + q * 8;

        float4 x0 = *(const float4*)(pvi);
        float4 x1 = *(const float4*)(pvi + 4);
        float4 x2 = *(const float4*)(pvi + 32);
        float4 x3 = *(const float4*)(pvi + 36);
        float4 x4 = *(const float4*)(pvj);
        float4 x5 = *(const float4*)(pvj + 4);
        float4 x6 = *(const float4*)(pvj + 32);
        float4 x7 = *(const float4*)(pvj + 36);
        float4 x8 = *(const float4*)(pe);
        float4 x9 = *(const float4*)(pe + 4);

        bf16x8 af[5];
        af[0] = cvt8(x0, x1);
        af[1] = cvt8(x2, x3);
        af[2] = cvt8(x4, x5);
        af[3] = cvt8(x6, x7);
        af[4] = cvt8(x8, x9);

        // ---- GEMM1: [16x160] @ [160x64] ----
        f32x4 acc[4] = {{0.f,0.f,0.f,0.f},{0.f,0.f,0.f,0.f},
                        {0.f,0.f,0.f,0.f},{0.f,0.f,0.f,0.f}};
        #pragma unroll
        for (int s = 0; s < 5; ++s) {
            #pragma unroll
            for (int n = 0; n < 4; ++n) {
                bf16x8 bf = *(const bf16x8*)&w1f[((s * 4 + n) * 64 + lane) * 8];
                acc[n] = __builtin_amdgcn_mfma_f32_16x16x32_bf16(af[s], bf, acc[n], 0, 0, 0);
            }
        }

        // ---- bias + ReLU, C/D-layout -> LDS (row = q*4+g, col = n*16+r) ----
        #pragma unroll
        for (int n = 0; n < 4; ++n) {
            #pragma unroll
            for (int g = 0; g < 4; ++g) {
                float h = acc[n][g] + b1v[n];
                h = h > 0.f ? h : 0.f;
                hb[(q * 4 + g) * 72 + n * 16 + r] = (__bf16)h;
            }
        }

        // make this wave's LDS writes visible to its own cross-lane reads
        asm volatile("s_waitcnt lgkmcnt(0)" ::: "memory");

        // ---- H as A-operand: m = r, k = s*32 + q*8 + j ----
        bf16x8 hf0 = *(const bf16x8*)&hb[r * 72 + q * 8];
        bf16x8 hf1 = *(const bf16x8*)&hb[r * 72 + 32 + q * 8];

        // ---- GEMM2: [16x64] @ [64x64] ----
        f32x4 acc2[4] = {{0.f,0.f,0.f,0.f},{0.f,0.f,0.f,0.f},
                         {0.f,0.f,0.f,0.f},{0.f,0.f,0.f,0.f}};
        #pragma unroll
        for (int n = 0; n < 4; ++n) {
            bf16x8 bf = *(const bf16x8*)&w2f[((0 * 4 + n) * 64 + lane) * 8];
            acc2[n] = __builtin_amdgcn_mfma_f32_16x16x32_bf16(hf0, bf, acc2[n], 0, 0, 0);
        }
        #pragma unroll
        for (int n = 0; n < 4; ++n) {
            bf16x8 bf = *(const bf16x8*)&w2f[((1 * 4 + n) * 64 + lane) * 8];
            acc2[n] = __builtin_amdgcn_mfma_f32_16x16x32_bf16(hf1, bf, acc2[n], 0, 0, 0);
        }

        // ---- epilogue: out[e0 + q*4 + g][n*16 + r] ----
        if (e0 + 16 <= (long long)E) {
            #pragma unroll
            for (int n = 0; n < 4; ++n) {
                #pragma unroll
                for (int g = 0; g < 4; ++g) {
                    out[(e0 + q * 4 + g) * 64 + n * 16 + r] = acc2[n][g] + b2v[n];
                }
            }
        } else {
            #pragma unroll
            for (int n = 0; n < 4; ++n) {
                #pragma unroll
                for (int g = 0; g < 4; ++g) {
                    long long m = e0 + q * 4 + g;
                    if (m < (long long)E)
                        out[m * 64 + n * 16 + r] = acc2[n][g] + b2v[n];
                }
            }
        }
    }
}

extern "C" void kernel_launch(void* const* d_in, const int* in_sizes, int n_in,
                              void* d_out, int out_size, void* d_ws, size_t ws_size,
                              hipStream_t stream) {
    const float* v_i  = (const float*)d_in[0];
    const float* v_j  = (const float*)d_in[1];
    const float* e_ij = (const float*)d_in[2];
    const float* W1   = (const float*)d_in[3];
    const float* b1   = (const float*)d_in[4];
    const float* W2   = (const float*)d_in[5];
    const float* b2   = (const float*)d_in[6];
    float* out = (float*)d_out;

    const int E = in_sizes[0] / 64;

    // 1024 blocks x 4 waves: grid-stride over 62500 16-edge tiles.
    edge_mlp_kernel<<<dim3(1024), dim3(256), 0, stream>>>(
        v_i, v_j, e_ij, W1, b1, W2, b2, out, E);
}